// Round 22
// baseline (597.986 us; speedup 1.0000x reference)
//
#include <hip/hip_runtime.h>
#include <stdint.h>

typedef unsigned short u16;
typedef __attribute__((ext_vector_type(8))) short bfrag;   // 8 bf16 = 4 VGPR
typedef __attribute__((ext_vector_type(4))) float f32x4;   // MFMA C/D
typedef __attribute__((ext_vector_type(2))) float f32x2;

__device__ __forceinline__ uint32_t pack2bf(float x, float y) {
  uint32_t bx = __float_as_uint(x), by = __float_as_uint(y);
  bx += 0x7fffu + ((bx >> 16) & 1u);
  by += 0x7fffu + ((by >> 16) & 1u);
  return (bx >> 16) | (by & 0xffff0000u);
}
__device__ __forceinline__ u16 f2bf(float x) {
  uint32_t b = __float_as_uint(x);
  b += 0x7fffu + ((b >> 16) & 1u);
  return (u16)(b >> 16);
}
__device__ __forceinline__ float bflo(uint32_t p) { return __uint_as_float(p << 16); }
__device__ __forceinline__ float bfhi(uint32_t p) { return __uint_as_float(p & 0xffff0000u); }

// ---- W[l][k][c] (f32) -> Wt[l][br][c][k] (bf16) ----
__global__ void k_cvt_w(const float* __restrict__ wp, const float* __restrict__ wn,
                        u16* __restrict__ wt, int total) {
  int i = blockIdx.x * blockDim.x + threadIdx.x;
  if (i >= total) return;
  int l = i >> 15;
  int rem = i & 32767;
  int br = rem >> 14;
  int rem2 = rem & 16383;
  int c = rem2 >> 7;
  int k = rem2 & 127;
  const float* w = br ? wn : wp;
  wt[i] = f2bf(w[l * 16384 + k * 128 + c]);
}

// ---- pre-scaled fp8 shadows direct from f32 x: X8p = dp*x, X8n = dn*x ----
__global__ void k_shadow(const float* __restrict__ x, const float* __restrict__ dpn,
                         uint8_t* __restrict__ x8p, uint8_t* __restrict__ x8n, int n) {
  int gid = blockIdx.x * blockDim.x + threadIdx.x;
  int nd = gid >> 6, lane = gid & 63;
  if (nd >= n) return;
  float dp = dpn[2 * nd], dn = dpn[2 * nd + 1];
  float2 v = ((const float2*)x)[(size_t)nd * 64 + lane];
  *(u16*)(x8p + (size_t)nd * 128 + lane * 2) =
      (u16)(__builtin_amdgcn_cvt_pk_fp8_f32(dp * v.x, dp * v.y, 0u, false) & 0xffffu);
  *(u16*)(x8n + (size_t)nd * 128 + lane * 2) =
      (u16)(__builtin_amdgcn_cvt_pk_fp8_f32(dn * v.x, dn * v.y, 0u, false) & 0xffffu);
}

// ---- pass A: per-block LDS histogram over coarse buckets (64 nodes each) ----
__global__ __launch_bounds__(256) void k_histA(
    const int* __restrict__ ei, const float* __restrict__ ew,
    int* __restrict__ histA, int E, int nbk, int nba) {
  __shared__ int h[1600];
  int blk = blockIdx.x, t = threadIdx.x;
  for (int b = t; b < nbk; b += 256) h[b] = 0;
  __syncthreads();
  int base = blk * 8192;
  int lim = base + 8192; if (lim > E) lim = E;
  for (int e = base + t; e < lim; e += 256) {
    if (ew[e] == 0.f) continue;
    atomicAdd(&h[ei[E + e] >> 6], 1);
  }
  __syncthreads();
  for (int b = t; b < nbk; b += 256) histA[(size_t)b * nba + blk] = h[b];
}

// ---- hierarchical exclusive scan over SM entries ----
__global__ void k_scan1(const int* __restrict__ cnt, int* __restrict__ offs,
                        int* __restrict__ part, int M) {
  __shared__ int sh[1024];
  int t = threadIdx.x;
  int i = blockIdx.x * 1024 + t;
  int v = (i < M) ? cnt[i] : 0;
  sh[t] = v;
  __syncthreads();
  for (int off = 1; off < 1024; off <<= 1) {
    int add = (t >= off) ? sh[t - off] : 0;
    __syncthreads();
    sh[t] += add;
    __syncthreads();
  }
  if (i < M) offs[i] = sh[t] - v;   // exclusive within block
  if (t == 1023) part[blockIdx.x] = sh[1023];
}
// parallel scan of block partials; writes offs[M]=total + 32 zero pad records
__global__ void k_scan2(int* __restrict__ part, int* __restrict__ offs,
                        uint32_t* __restrict__ recF, int nb, int M) {
  __shared__ int sh[1024];
  int t = threadIdx.x;
  int v = (t < nb) ? part[t] : 0;
  sh[t] = v;
  __syncthreads();
  for (int off = 1; off < 1024; off <<= 1) {
    int add = (t >= off) ? sh[t - off] : 0;
    __syncthreads();
    sh[t] += add;
    __syncthreads();
  }
  if (t < nb) part[t] = sh[t] - v;   // exclusive
  if (t == 1023) {
    int run = sh[1023];
    offs[M] = run;
    for (int i = 0; i < 32; ++i) recF[run + i] = 0u;
  }
}

// ---- pass B: scatter packed records {dl:6 | sign:1 | src:17}, 8192 edges/block ----
__global__ __launch_bounds__(256) void k_partB(
    const int* __restrict__ ei, const float* __restrict__ ew,
    const int* __restrict__ offsA, const int* __restrict__ partA,
    uint32_t* __restrict__ rec4, int E, int nbk, int nba) {
  __shared__ int curs[1600];
  int blk = blockIdx.x, t = threadIdx.x;
  for (int b = t; b < nbk; b += 256) {
    int idx = b * nba + blk;
    curs[b] = offsA[idx] + partA[idx >> 10];
  }
  __syncthreads();
  int base = blk * 8192;
  int lim = base + 8192; if (lim > E) lim = E;
  for (int e = base + t; e < lim; e += 256) {
    float w = ew[e];
    if (w == 0.f) continue;
    int s = ei[e], d = ei[E + e];
    int pos = atomicAdd(&curs[d >> 6], 1);
    rec4[pos] = (uint32_t)s | ((w < 0.f ? 1u : 0u) << 17) | ((uint32_t)(d & 63) << 18);
  }
}

// ---- pass C: per-bucket LDS counting sort -> dst+sign-grouped records + bnd2 + dpn ----
// key = dl*2 + sign  =>  within each node, pos records precede neg records.
__global__ __launch_bounds__(256) void k_sortC(
    const uint32_t* __restrict__ rec4, const int* __restrict__ offsA,
    const int* __restrict__ partA, uint32_t* __restrict__ recF,
    int* __restrict__ bnd2, float* __restrict__ dpn,
    int n, int nbk, int nba, int SM) {
  __shared__ uint32_t rin[3072];
  __shared__ uint32_t rout[3072];
  __shared__ int hist[128];
  __shared__ int curs[128];
  int b = blockIdx.x, t = threadIdx.x;
  int i0 = b * nba;
  int beg = offsA[i0] + partA[i0 >> 10];
  int end;
  if (b + 1 < nbk) {
    int i1 = (b + 1) * nba;
    end = offsA[i1] + partA[i1 >> 10];
  } else {
    end = offsA[SM];
  }
  int cnt = end - beg;
  if (cnt > 3072) cnt = 3072;   // statistically impossible for uniform dst; memory-safety clamp
  for (int i = t; i < cnt; i += 256) rin[i] = rec4[beg + i];
  if (t < 128) hist[t] = 0;
  __syncthreads();
  for (int i = t; i < cnt; i += 256)
    atomicAdd(&hist[(rin[i] >> 17) & 127], 1);   // key = dl*2 + sign
  __syncthreads();
  if (t == 0) {
    int run = 0;
    for (int k = 0; k < 128; ++k) { int c = hist[k]; curs[k] = run; run += c; }
  }
  __syncthreads();
  if (t < 64) {
    int node = b * 64 + t;
    if (node < n) {
      bnd2[2 * node]     = beg + curs[t * 2];      // pos start
      bnd2[2 * node + 1] = beg + curs[t * 2 + 1];  // neg start (= pos end)
      int degp = hist[t * 2], degn = hist[t * 2 + 1];
      dpn[2 * node]     = rsqrtf(1.f + (float)degp);
      dpn[2 * node + 1] = rsqrtf(1.f + (float)degn);
    }
  }
  if (t == 0 && b == nbk - 1) bnd2[2 * n] = end;
  __syncthreads();
  for (int i = t; i < cnt; i += 256) {
    uint32_t r = rin[i];
    int pos = atomicAdd(&curs[(r >> 17) & 127], 1);
    rout[pos] = r & 0x1FFFFu;   // src only; sign is positional now
  }
  __syncthreads();
  for (int i = t; i < cnt; i += 256) recF[beg + i] = rout[i];
}

// ---- aggregation: split-wave u32 gathers (2 edges / instr), sign-split sums ----
// lane = (eg = lane>>5: edge half, fl = lane&31: feature quad of 4 fp8)
__global__ __launch_bounds__(256) void k_agg(
    const uint8_t* __restrict__ x8p, const uint8_t* __restrict__ x8n,
    const int* __restrict__ bnd2, const uint32_t* __restrict__ rec,
    const float* __restrict__ dpn,
    uint32_t* __restrict__ up, uint32_t* __restrict__ un, int n) {
  int gid = blockIdx.x * blockDim.x + threadIdx.x;
  int nd = gid >> 6, lane = gid & 63;
  if (nd >= n) return;
  int eg = lane >> 5, fl = lane & 31;
  int beg = bnd2[2 * nd], mid = bnd2[2 * nd + 1], end = bnd2[2 * nd + 2];
  float ap[4] = {0.f, 0.f, 0.f, 0.f}, an[4] = {0.f, 0.f, 0.f, 0.f};
  // positive branch: rows pre-scaled by dp[s]
  for (int j = beg; j < mid; j += 8) {
    uint32_t rr[8];
#pragma unroll
    for (int u = 0; u < 8; ++u) rr[u] = rec[j + u];   // over-read: masked / 32 pads
    uint32_t pw[4];
#pragma unroll
    for (int u = 0; u < 4; ++u) {
      uint32_t r = eg ? rr[2 * u + 1] : rr[2 * u];
      pw[u] = *(const uint32_t*)(x8p + (size_t)r * 128 + fl * 4);
    }
#pragma unroll
    for (int u = 0; u < 4; ++u) {
      uint32_t wm = (j + 2 * u + eg < mid) ? pw[u] : 0u;   // u32 of 4 fp8 zeros == 0.0
      f32x2 lo = __builtin_amdgcn_cvt_pk_f32_fp8(wm, false);
      f32x2 hi = __builtin_amdgcn_cvt_pk_f32_fp8(wm, true);
      ap[0] += lo.x; ap[1] += lo.y; ap[2] += hi.x; ap[3] += hi.y;
    }
  }
  // negative branch: rows pre-scaled by dn[s]
  for (int j = mid; j < end; j += 8) {
    uint32_t rr[8];
#pragma unroll
    for (int u = 0; u < 8; ++u) rr[u] = rec[j + u];
    uint32_t pw[4];
#pragma unroll
    for (int u = 0; u < 4; ++u) {
      uint32_t r = eg ? rr[2 * u + 1] : rr[2 * u];
      pw[u] = *(const uint32_t*)(x8n + (size_t)r * 128 + fl * 4);
    }
#pragma unroll
    for (int u = 0; u < 4; ++u) {
      uint32_t wm = (j + 2 * u + eg < end) ? pw[u] : 0u;
      f32x2 lo = __builtin_amdgcn_cvt_pk_f32_fp8(wm, false);
      f32x2 hi = __builtin_amdgcn_cvt_pk_f32_fp8(wm, true);
      an[0] += lo.x; an[1] += lo.y; an[2] += hi.x; an[3] += hi.y;
    }
  }
  // fold the two edge halves
#pragma unroll
  for (int k = 0; k < 4; ++k) {
    ap[k] += __shfl_xor(ap[k], 32, 64);
    an[k] += __shfl_xor(an[k], 32, 64);
  }
  // self term from shadows: x8p[nd] = dp_d*h  =>  U = dpd*(ap + self)
  float dpd = dpn[2 * nd], dnd = dpn[2 * nd + 1];
  if (eg == 0) {
    uint32_t sw = *(const uint32_t*)(x8p + (size_t)nd * 128 + fl * 4);
    f32x2 lo = __builtin_amdgcn_cvt_pk_f32_fp8(sw, false);
    f32x2 hi = __builtin_amdgcn_cvt_pk_f32_fp8(sw, true);
    uint2 o;
    o.x = pack2bf(dpd * (ap[0] + lo.x), dpd * (ap[1] + lo.y));
    o.y = pack2bf(dpd * (ap[2] + hi.x), dpd * (ap[3] + hi.y));
    *(uint2*)(up + (size_t)nd * 64 + fl * 2) = o;
  } else {
    uint32_t sw = *(const uint32_t*)(x8n + (size_t)nd * 128 + fl * 4);
    f32x2 lo = __builtin_amdgcn_cvt_pk_f32_fp8(sw, false);
    f32x2 hi = __builtin_amdgcn_cvt_pk_f32_fp8(sw, true);
    uint2 o;
    o.x = pack2bf(dnd * (an[0] + lo.x), dnd * (an[1] + lo.y));
    o.y = pack2bf(dnd * (an[2] + hi.x), dnd * (an[3] + hi.y));
    *(uint2*)(un + (size_t)nd * 64 + fl * 2) = o;
  }
}

// ---- fused dual GEMM + bias + relu-diff, persistent blocks ----
// l < L-1: emit only pre-scaled fp8 shadows (no bf16 h).  l == L-1: fused pooling.
__global__ __launch_bounds__(256, 2) void k_gemm(
    const short* __restrict__ up, const short* __restrict__ un,
    const u16* __restrict__ wt, const float* __restrict__ bp, const float* __restrict__ bn,
    const float* __restrict__ dpn, const int* __restrict__ batch,
    uint8_t* __restrict__ x8p, uint8_t* __restrict__ x8n,
    float* __restrict__ pooled, int do_pool, int nrows, int nchunks) {
  __shared__ __align__(16) u16 wl[32768];          // 64 KB: Wt_pos | Wt_neg, swizzled
  __shared__ __align__(16) uint8_t ct8[4][8][144]; // 4.5 KB: per-wave fp8 staging (reused p,n)
  __shared__ float pacc[128];                      // pooling accumulator (do_pool)
  int t = threadIdx.x;
  for (int i = t; i < 4096; i += 256) {    // 4096 x 16B chunks
    int ci = i & 2047;
    int col = ci >> 4, kc16 = ci & 15;
    int db = (i >> 11) * 32768 + ((col * 256 + kc16 * 16) ^ ((col & 7) << 4));
    *(uint4*)((char*)wl + db) = ((const uint4*)wt)[i];
  }
  __syncthreads();
  int wv = t >> 6, lane = t & 63;
  int l15 = lane & 15, l4 = lane >> 4;
  float vbp[8], vbn[8];
#pragma unroll
  for (int nt = 0; nt < 8; ++nt) {
    vbp[nt] = bp[nt * 16 + l15];
    vbn[nt] = bn[nt * 16 + l15];
  }
  for (int c = blockIdx.x; c < nchunks; c += gridDim.x) {
    int rowbase = c * 128 + wv * 32;
    int r0 = rowbase + l15;      if (r0 >= nrows) r0 = nrows - 1;
    int r1 = rowbase + 16 + l15; if (r1 >= nrows) r1 = nrows - 1;
    f32x4 accP[2][8], accN[2][8];
#pragma unroll
    for (int rt = 0; rt < 2; ++rt)
#pragma unroll
      for (int nt = 0; nt < 8; ++nt) { accP[rt][nt] = (f32x4)(0.f); accN[rt][nt] = (f32x4)(0.f); }
#pragma unroll
    for (int kc = 0; kc < 4; ++kc) {
      int koff = kc * 32 + l4 * 8;
      bfrag aP0 = *(const bfrag*)(up + (size_t)r0 * 128 + koff);
      bfrag aP1 = *(const bfrag*)(up + (size_t)r1 * 128 + koff);
      bfrag aN0 = *(const bfrag*)(un + (size_t)r0 * 128 + koff);
      bfrag aN1 = *(const bfrag*)(un + (size_t)r1 * 128 + koff);
#pragma unroll
      for (int nt = 0; nt < 8; ++nt) {
        int col = nt * 16 + l15;
        int bb = (col * 256 + kc * 64 + l4 * 16) ^ ((col & 7) << 4);
        bfrag bP = *(const bfrag*)((const char*)wl + bb);
        bfrag bN = *(const bfrag*)((const char*)wl + 32768 + bb);
        accP[0][nt] = __builtin_amdgcn_mfma_f32_16x16x32_bf16(aP0, bP, accP[0][nt], 0, 0, 0);
        accP[1][nt] = __builtin_amdgcn_mfma_f32_16x16x32_bf16(aP1, bP, accP[1][nt], 0, 0, 0);
        accN[0][nt] = __builtin_amdgcn_mfma_f32_16x16x32_bf16(aN0, bN, accN[0][nt], 0, 0, 0);
        accN[1][nt] = __builtin_amdgcn_mfma_f32_16x16x32_bf16(aN1, bN, accN[1][nt], 0, 0, 0);
      }
    }
    if (do_pool) {
      // ---- fused mean-pool partial sums (last layer): no global h writes ----
      int crow0 = c * 128;
      int crow1 = crow0 + 127; if (crow1 >= nrows) crow1 = nrows - 1;
      int g0 = batch[crow0], g1 = batch[crow1];
      if (t < 128) pacc[t] = 0.f;
      __syncthreads();
      if (g0 == g1) {
#pragma unroll
        for (int nt = 0; nt < 8; ++nt) {
          float s = 0.f;
#pragma unroll
          for (int rt = 0; rt < 2; ++rt) {
#pragma unroll
            for (int r = 0; r < 4; ++r) {
              int row = rowbase + rt * 16 + l4 * 4 + r;
              float vp = accP[rt][nt][r] + vbp[nt]; vp = vp > 0.f ? vp : 0.f;
              float vn = accN[rt][nt][r] + vbn[nt]; vn = vn > 0.f ? vn : 0.f;
              s += (row < nrows) ? (vp - vn) : 0.f;
            }
          }
          s += __shfl_xor(s, 16, 64);
          s += __shfl_xor(s, 32, 64);
          if (l4 == 0) atomicAdd(&pacc[nt * 16 + l15], s);
        }
        __syncthreads();
        if (t < 128) atomicAdd(&pooled[g0 * 128 + t], pacc[t]);
      } else {
        for (int g = g0; g <= g1; ++g) {
#pragma unroll
          for (int nt = 0; nt < 8; ++nt) {
            float s = 0.f;
#pragma unroll
            for (int rt = 0; rt < 2; ++rt) {
#pragma unroll
              for (int r = 0; r < 4; ++r) {
                int row = rowbase + rt * 16 + l4 * 4 + r;
                bool in = (row < nrows) && (batch[row] == g);
                float vp = accP[rt][nt][r] + vbp[nt]; vp = vp > 0.f ? vp : 0.f;
                float vn = accN[rt][nt][r] + vbn[nt]; vn = vn > 0.f ? vn : 0.f;
                s += in ? (vp - vn) : 0.f;
              }
            }
            s += __shfl_xor(s, 16, 64);
            s += __shfl_xor(s, 32, 64);
            if (l4 == 0) atomicAdd(&pooled[g * 128 + nt * 16 + l15], s);
          }
        }
        __syncthreads();   // keep barrier count uniform with fast path
      }
      __syncthreads();     // pacc reuse guard for next chunk
      continue;
    }
    // epilogue: fp8 shadows only (two phases through the same ct8 buffer)
#pragma unroll
    for (int rt = 0; rt < 2; ++rt) {
#pragma unroll
      for (int h = 0; h < 2; ++h) {
        if ((l4 >> 1) == h) {
          int lr = (l4 & 1) * 4;
#pragma unroll
          for (int r = 0; r < 4; ++r) {
            int rw = rowbase + rt * 16 + h * 8 + lr + r;
            if (rw >= nrows) rw = nrows - 1;
            float dpr = dpn[2 * rw];
#pragma unroll
            for (int nt = 0; nt < 8; ++nt) {
              int col = nt * 16 + l15;
              float vp = accP[rt][nt][r] + vbp[nt]; vp = vp > 0.f ? vp : 0.f;
              float vn = accN[rt][nt][r] + vbn[nt]; vn = vn > 0.f ? vn : 0.f;
              float hv = vp - vn;
              ct8[wv][lr + r][col] =
                  (uint8_t)(__builtin_amdgcn_cvt_pk_fp8_f32(dpr * hv, dpr * hv, 0u, false) & 0xffu);
            }
          }
        }
        {
          int lrow = lane >> 3, lch = lane & 7;
          int grow = rowbase + rt * 16 + h * 8 + lrow;
          uint4 b16 = *(const uint4*)&ct8[wv][lrow][lch * 16];
          if (grow < nrows)
            *(uint4*)(x8p + (size_t)grow * 128 + lch * 16) = b16;
        }
        // phase 2: n-shadow
        if ((l4 >> 1) == h) {
          int lr = (l4 & 1) * 4;
#pragma unroll
          for (int r = 0; r < 4; ++r) {
            int rw = rowbase + rt * 16 + h * 8 + lr + r;
            if (rw >= nrows) rw = nrows - 1;
            float dnr = dpn[2 * rw + 1];
#pragma unroll
            for (int nt = 0; nt < 8; ++nt) {
              int col = nt * 16 + l15;
              float vp = accP[rt][nt][r] + vbp[nt]; vp = vp > 0.f ? vp : 0.f;
              float vn = accN[rt][nt][r] + vbn[nt]; vn = vn > 0.f ? vn : 0.f;
              float hv = vp - vn;
              ct8[wv][lr + r][col] =
                  (uint8_t)(__builtin_amdgcn_cvt_pk_fp8_f32(dnr * hv, dnr * hv, 0u, false) & 0xffu);
            }
          }
        }
        {
          int lrow = lane >> 3, lch = lane & 7;
          int grow = rowbase + rt * 16 + h * 8 + lrow;
          uint4 b16 = *(const uint4*)&ct8[wv][lrow][lch * 16];
          if (grow < nrows)
            *(uint4*)(x8n + (size_t)grow * 128 + lch * 16) = b16;
        }
      }
    }
  }
}

// ---- LayerNorm over D=128, one wave per graph; count via binary search ----
__global__ void k_ln(const float* __restrict__ pooled, const int* __restrict__ batch,
                     const float* __restrict__ gamma, const float* __restrict__ beta,
                     float* __restrict__ out, int G, int n) {
  int gid = blockIdx.x * blockDim.x + threadIdx.x;
  int g = gid >> 6, lane = gid & 63;
  if (g >= G) return;
  int lo = 0, hi = n;
  while (lo < hi) { int m = (lo + hi) >> 1; if (batch[m] < g) lo = m + 1; else hi = m; }
  int s0 = lo;
  lo = s0; hi = n;
  while (lo < hi) { int m = (lo + hi) >> 1; if (batch[m] < g + 1) lo = m + 1; else hi = m; }
  int e0 = lo;
  float2 s = ((const float2*)pooled)[g * 64 + lane];
  float cm = fmaxf((float)(e0 - s0), 1.f);
  float v0 = s.x / cm, v1 = s.y / cm;
  float tsum = v0 + v1;
#pragma unroll
  for (int m = 1; m < 64; m <<= 1) tsum += __shfl_xor(tsum, m, 64);
  float mu = tsum * (1.f / 128.f);
  float d0 = v0 - mu, d1 = v1 - mu;
  float q = d0 * d0 + d1 * d1;
#pragma unroll
  for (int m = 1; m < 64; m <<= 1) q += __shfl_xor(q, m, 64);
  float inv = rsqrtf(q * (1.f / 128.f) + 1e-5f);
  int f = 2 * lane;
  out[g * 128 + f]     = d0 * inv * gamma[f]     + beta[f];
  out[g * 128 + f + 1] = d1 * inv * gamma[f + 1] + beta[f + 1];
}

extern "C" void kernel_launch(void* const* d_in, const int* in_sizes, int n_in,
                              void* d_out, int out_size, void* d_ws, size_t ws_size,
                              hipStream_t stream) {
  const float* x     = (const float*)d_in[0];
  const int* ei      = (const int*)d_in[1];   // harness converts int64 -> int32
  const float* ew    = (const float*)d_in[2];
  const int* bt      = (const int*)d_in[3];   // int32
  const float* Wp    = (const float*)d_in[4];
  const float* bp    = (const float*)d_in[5];
  const float* Wn    = (const float*)d_in[6];
  const float* bn    = (const float*)d_in[7];
  const float* gamma = (const float*)d_in[8];
  const float* beta  = (const float*)d_in[9];
  int N = in_sizes[0] / 128;
  int E = in_sizes[1] / 2;
  int L = in_sizes[4] / (128 * 128);
  int G = out_size / 128;
  int nbk = (N + 63) / 64;          // coarse buckets (64 nodes)
  int nba = (E + 8191) / 8192;      // hist/part blocks (8k edges each)
  int SM = nbk * nba;               // scan size

  char* w = (char*)d_ws;
  auto alloc = [&](size_t bytes) {
    char* p = w;
    w += (bytes + 255) & ~(size_t)255;
    return p;
  };
  uint8_t* X8p   = (uint8_t*)alloc((size_t)N * 128 + 256); // dp[s]*h (fp8)
  uint8_t* X8n   = (uint8_t*)alloc((size_t)N * 128 + 256); // dn[s]*h (fp8)
  uint32_t* U    = (uint32_t*)alloc((size_t)N * 128 * 2);  // pos-branch agg (bf16)
  uint32_t* V    = (uint32_t*)alloc((size_t)N * 128 * 2);  // neg-branch agg (bf16)
  u16* wt        = (u16*)alloc((size_t)L * 2 * 128 * 128 * 2);
  uint32_t* rec4 = (uint32_t*)alloc(((size_t)E + 32) * 4); // bucket-major packed
  uint32_t* recF = (uint32_t*)alloc(((size_t)E + 32) * 4); // dst+sign-grouped final
  int* histA     = (int*)alloc((size_t)SM * 4);
  int* offsA     = (int*)alloc((size_t)(SM + 1) * 4);
  int* partA     = (int*)alloc(1024 * 4);
  int* bnd2      = (int*)alloc((size_t)(2 * N + 1) * 4);
  float* dpn     = (float*)alloc((size_t)N * 8);
  float* pooled  = (float*)alloc((size_t)G * 128 * 4);

  hipMemsetAsync(pooled, 0, (size_t)G * 128 * 4, stream);

  int wtot = L * 2 * 128 * 128;
  k_cvt_w<<<(wtot + 255) / 256, 256, 0, stream>>>(Wp, Wn, wt, wtot);
  k_histA<<<nba, 256, 0, stream>>>(ei, ew, histA, E, nbk, nba);
  int NB1 = (SM + 1023) / 1024;
  k_scan1<<<NB1, 1024, 0, stream>>>(histA, offsA, partA, SM);
  k_scan2<<<1, 1024, 0, stream>>>(partA, offsA, recF, NB1, SM);
  k_partB<<<nba, 256, 0, stream>>>(ei, ew, offsA, partA, rec4, E, nbk, nba);
  k_sortC<<<nbk, 256, 0, stream>>>(rec4, offsA, partA, recF, bnd2, dpn, N, nbk, nba, SM);
  k_shadow<<<((size_t)N * 64 + 255) / 256, 256, 0, stream>>>(x, dpn, X8p, X8n, N);

  int nchunks = (N + 127) / 128;
  for (int l = 0; l < L; ++l) {
    k_agg<<<((size_t)N * 64 + 255) / 256, 256, 0, stream>>>(X8p, X8n, bnd2, recF, dpn, U, V, N);
    k_gemm<<<512, 256, 0, stream>>>((const short*)U, (const short*)V,
                                    wt + (size_t)l * 32768, bp + (size_t)l * 128,
                                    bn + (size_t)l * 128, dpn, bt,
                                    X8p, X8n, pooled, (l == L - 1) ? 1 : 0,
                                    N, nchunks);
  }
  k_ln<<<(G * 64 + 255) / 256, 256, 0, stream>>>(pooled, bt, gamma, beta, (float*)d_out, G, N);
}

// Round 23
// 527.753 us; speedup vs baseline: 1.1331x; 1.1331x over previous
//
#include <hip/hip_runtime.h>
#include <stdint.h>

typedef unsigned short u16;
typedef __attribute__((ext_vector_type(8))) short bfrag;   // 8 bf16 = 4 VGPR
typedef __attribute__((ext_vector_type(4))) float f32x4;   // MFMA C/D
typedef __attribute__((ext_vector_type(2))) float f32x2;

__device__ __forceinline__ uint32_t pack2bf(float x, float y) {
  uint32_t bx = __float_as_uint(x), by = __float_as_uint(y);
  bx += 0x7fffu + ((bx >> 16) & 1u);
  by += 0x7fffu + ((by >> 16) & 1u);
  return (bx >> 16) | (by & 0xffff0000u);
}
__device__ __forceinline__ u16 f2bf(float x) {
  uint32_t b = __float_as_uint(x);
  b += 0x7fffu + ((b >> 16) & 1u);
  return (u16)(b >> 16);
}
__device__ __forceinline__ float bflo(uint32_t p) { return __uint_as_float(p << 16); }
__device__ __forceinline__ float bfhi(uint32_t p) { return __uint_as_float(p & 0xffff0000u); }

// ---- W[l][k][c] (f32) -> Wt[l][br][c][k] (bf16) ----
__global__ void k_cvt_w(const float* __restrict__ wp, const float* __restrict__ wn,
                        u16* __restrict__ wt, int total) {
  int i = blockIdx.x * blockDim.x + threadIdx.x;
  if (i >= total) return;
  int l = i >> 15;
  int rem = i & 32767;
  int br = rem >> 14;
  int rem2 = rem & 16383;
  int c = rem2 >> 7;
  int k = rem2 & 127;
  const float* w = br ? wn : wp;
  wt[i] = f2bf(w[l * 16384 + k * 128 + c]);
}

// ---- pre-scaled fp8 shadows direct from f32 x: X8p = dp*x, X8n = dn*x ----
__global__ void k_shadow(const float* __restrict__ x, const float* __restrict__ dpn,
                         uint8_t* __restrict__ x8p, uint8_t* __restrict__ x8n, int n) {
  int gid = blockIdx.x * blockDim.x + threadIdx.x;
  int nd = gid >> 6, lane = gid & 63;
  if (nd >= n) return;
  float dp = dpn[2 * nd], dn = dpn[2 * nd + 1];
  float2 v = ((const float2*)x)[(size_t)nd * 64 + lane];
  *(u16*)(x8p + (size_t)nd * 128 + lane * 2) =
      (u16)(__builtin_amdgcn_cvt_pk_fp8_f32(dp * v.x, dp * v.y, 0u, false) & 0xffffu);
  *(u16*)(x8n + (size_t)nd * 128 + lane * 2) =
      (u16)(__builtin_amdgcn_cvt_pk_fp8_f32(dn * v.x, dn * v.y, 0u, false) & 0xffffu);
}

// ---- pass A: per-block LDS histogram over coarse buckets (64 nodes each) ----
__global__ __launch_bounds__(256) void k_histA(
    const int* __restrict__ ei, const float* __restrict__ ew,
    int* __restrict__ histA, int E, int nbk, int nba) {
  __shared__ int h[1600];
  int blk = blockIdx.x, t = threadIdx.x;
  for (int b = t; b < nbk; b += 256) h[b] = 0;
  __syncthreads();
  int base = blk * 8192;
  int lim = base + 8192; if (lim > E) lim = E;
  for (int e = base + t; e < lim; e += 256) {
    if (ew[e] == 0.f) continue;
    atomicAdd(&h[ei[E + e] >> 6], 1);
  }
  __syncthreads();
  for (int b = t; b < nbk; b += 256) histA[(size_t)b * nba + blk] = h[b];
}

// ---- hierarchical exclusive scan over SM entries ----
__global__ void k_scan1(const int* __restrict__ cnt, int* __restrict__ offs,
                        int* __restrict__ part, int M) {
  __shared__ int sh[1024];
  int t = threadIdx.x;
  int i = blockIdx.x * 1024 + t;
  int v = (i < M) ? cnt[i] : 0;
  sh[t] = v;
  __syncthreads();
  for (int off = 1; off < 1024; off <<= 1) {
    int add = (t >= off) ? sh[t - off] : 0;
    __syncthreads();
    sh[t] += add;
    __syncthreads();
  }
  if (i < M) offs[i] = sh[t] - v;   // exclusive within block
  if (t == 1023) part[blockIdx.x] = sh[1023];
}
// parallel scan of block partials; writes offs[M]=total + 32 zero pad records
__global__ void k_scan2(int* __restrict__ part, int* __restrict__ offs,
                        uint32_t* __restrict__ recF, int nb, int M) {
  __shared__ int sh[1024];
  int t = threadIdx.x;
  int v = (t < nb) ? part[t] : 0;
  sh[t] = v;
  __syncthreads();
  for (int off = 1; off < 1024; off <<= 1) {
    int add = (t >= off) ? sh[t - off] : 0;
    __syncthreads();
    sh[t] += add;
    __syncthreads();
  }
  if (t < nb) part[t] = sh[t] - v;   // exclusive
  if (t == 1023) {
    int run = sh[1023];
    offs[M] = run;
    for (int i = 0; i < 32; ++i) recF[run + i] = 0u;
  }
}

// ---- pass B: scatter packed records {dl:6 | sign:1 | src:17}, 8192 edges/block ----
__global__ __launch_bounds__(256) void k_partB(
    const int* __restrict__ ei, const float* __restrict__ ew,
    const int* __restrict__ offsA, const int* __restrict__ partA,
    uint32_t* __restrict__ rec4, int E, int nbk, int nba) {
  __shared__ int curs[1600];
  int blk = blockIdx.x, t = threadIdx.x;
  for (int b = t; b < nbk; b += 256) {
    int idx = b * nba + blk;
    curs[b] = offsA[idx] + partA[idx >> 10];
  }
  __syncthreads();
  int base = blk * 8192;
  int lim = base + 8192; if (lim > E) lim = E;
  for (int e = base + t; e < lim; e += 256) {
    float w = ew[e];
    if (w == 0.f) continue;
    int s = ei[e], d = ei[E + e];
    int pos = atomicAdd(&curs[d >> 6], 1);
    rec4[pos] = (uint32_t)s | ((w < 0.f ? 1u : 0u) << 17) | ((uint32_t)(d & 63) << 18);
  }
}

// ---- pass C: per-bucket LDS counting sort -> dst+sign-grouped records + bnd2 + dpn ----
// key = dl*2 + sign  =>  within each node, pos records precede neg records.
__global__ __launch_bounds__(256) void k_sortC(
    const uint32_t* __restrict__ rec4, const int* __restrict__ offsA,
    const int* __restrict__ partA, uint32_t* __restrict__ recF,
    int* __restrict__ bnd2, float* __restrict__ dpn,
    int n, int nbk, int nba, int SM) {
  __shared__ uint32_t rin[3072];
  __shared__ uint32_t rout[3072];
  __shared__ int hist[128];
  __shared__ int curs[128];
  int b = blockIdx.x, t = threadIdx.x;
  int i0 = b * nba;
  int beg = offsA[i0] + partA[i0 >> 10];
  int end;
  if (b + 1 < nbk) {
    int i1 = (b + 1) * nba;
    end = offsA[i1] + partA[i1 >> 10];
  } else {
    end = offsA[SM];
  }
  int cnt = end - beg;
  if (cnt > 3072) cnt = 3072;   // statistically impossible for uniform dst; memory-safety clamp
  for (int i = t; i < cnt; i += 256) rin[i] = rec4[beg + i];
  if (t < 128) hist[t] = 0;
  __syncthreads();
  for (int i = t; i < cnt; i += 256)
    atomicAdd(&hist[(rin[i] >> 17) & 127], 1);   // key = dl*2 + sign
  __syncthreads();
  if (t == 0) {
    int run = 0;
    for (int k = 0; k < 128; ++k) { int c = hist[k]; curs[k] = run; run += c; }
  }
  __syncthreads();
  if (t < 64) {
    int node = b * 64 + t;
    if (node < n) {
      bnd2[2 * node]     = beg + curs[t * 2];      // pos start
      bnd2[2 * node + 1] = beg + curs[t * 2 + 1];  // neg start (= pos end)
      int degp = hist[t * 2], degn = hist[t * 2 + 1];
      dpn[2 * node]     = rsqrtf(1.f + (float)degp);
      dpn[2 * node + 1] = rsqrtf(1.f + (float)degn);
    }
  }
  if (t == 0 && b == nbk - 1) bnd2[2 * n] = end;
  __syncthreads();
  for (int i = t; i < cnt; i += 256) {
    uint32_t r = rin[i];
    int pos = atomicAdd(&curs[(r >> 17) & 127], 1);
    rout[pos] = r & 0x1FFFFu;   // src only; sign is positional now
  }
  __syncthreads();
  for (int i = t; i < cnt; i += 256) recF[beg + i] = rout[i];
}

// ---- aggregation: sign-split SUM of pre-scaled fp8 rows; self term from shadows ----
__global__ __launch_bounds__(256) void k_agg(
    const uint8_t* __restrict__ x8p, const uint8_t* __restrict__ x8n,
    const int* __restrict__ bnd2, const uint32_t* __restrict__ rec,
    const float* __restrict__ dpn,
    uint32_t* __restrict__ up, uint32_t* __restrict__ un, int n) {
  int gid = blockIdx.x * blockDim.x + threadIdx.x;
  int nd = gid >> 6, lane = gid & 63;
  if (nd >= n) return;
  int beg = bnd2[2 * nd], mid = bnd2[2 * nd + 1], end = bnd2[2 * nd + 2];
  float ap0 = 0.f, ap1 = 0.f, an0 = 0.f, an1 = 0.f;
  // positive branch: rows already scaled by dp[s]
  for (int j = beg; j < mid; j += 8) {
    uint32_t rr[8]; u16 pk[8];
#pragma unroll
    for (int u = 0; u < 8; ++u) rr[u] = rec[j + u];   // over-read: masked / 32 pads
#pragma unroll
    for (int u = 0; u < 8; ++u)
      pk[u] = *(const u16*)(x8p + (size_t)rr[u] * 128 + lane * 2);
#pragma unroll
    for (int u = 0; u < 8; ++u) {
      u16 pm = (j + u < mid) ? pk[u] : (u16)0;        // fp8 0x00 == 0.0
      f32x2 v = __builtin_amdgcn_cvt_pk_f32_fp8((uint32_t)pm, false);
      ap0 += v.x;
      ap1 += v.y;
    }
  }
  // negative branch: rows already scaled by dn[s]
  for (int j = mid; j < end; j += 8) {
    uint32_t rr[8]; u16 pk[8];
#pragma unroll
    for (int u = 0; u < 8; ++u) rr[u] = rec[j + u];
#pragma unroll
    for (int u = 0; u < 8; ++u)
      pk[u] = *(const u16*)(x8n + (size_t)rr[u] * 128 + lane * 2);
#pragma unroll
    for (int u = 0; u < 8; ++u) {
      u16 pm = (j + u < end) ? pk[u] : (u16)0;
      f32x2 v = __builtin_amdgcn_cvt_pk_f32_fp8((uint32_t)pm, false);
      an0 += v.x;
      an1 += v.y;
    }
  }
  // self term: x8p[nd] = dp_d*h  =>  U = dpd*(ap + p_self); same for V
  float dpd = dpn[2 * nd], dnd = dpn[2 * nd + 1];
  u16 sp8 = *(const u16*)(x8p + (size_t)nd * 128 + lane * 2);
  u16 sn8 = *(const u16*)(x8n + (size_t)nd * 128 + lane * 2);
  f32x2 ps = __builtin_amdgcn_cvt_pk_f32_fp8((uint32_t)sp8, false);
  f32x2 ns = __builtin_amdgcn_cvt_pk_f32_fp8((uint32_t)sn8, false);
  up[(size_t)nd * 64 + lane] = pack2bf(dpd * (ap0 + ps.x), dpd * (ap1 + ps.y));
  un[(size_t)nd * 64 + lane] = pack2bf(dnd * (an0 + ns.x), dnd * (an1 + ns.y));
}

// ---- fused dual GEMM + bias + relu-diff, persistent blocks ----
// l < L-1: emit only pre-scaled fp8 shadows (no bf16 h).  l == L-1: fused pooling.
__global__ __launch_bounds__(256, 2) void k_gemm(
    const short* __restrict__ up, const short* __restrict__ un,
    const u16* __restrict__ wt, const float* __restrict__ bp, const float* __restrict__ bn,
    const float* __restrict__ dpn, const int* __restrict__ batch,
    uint8_t* __restrict__ x8p, uint8_t* __restrict__ x8n,
    float* __restrict__ pooled, int do_pool, int nrows, int nchunks) {
  __shared__ __align__(16) u16 wl[32768];          // 64 KB: Wt_pos | Wt_neg, swizzled
  __shared__ __align__(16) uint8_t ct8[4][8][144]; // 4.5 KB: per-wave fp8 staging (reused p,n)
  __shared__ float pacc[128];                      // pooling accumulator (do_pool)
  int t = threadIdx.x;
  for (int i = t; i < 4096; i += 256) {    // 4096 x 16B chunks
    int ci = i & 2047;
    int col = ci >> 4, kc16 = ci & 15;
    int db = (i >> 11) * 32768 + ((col * 256 + kc16 * 16) ^ ((col & 7) << 4));
    *(uint4*)((char*)wl + db) = ((const uint4*)wt)[i];
  }
  __syncthreads();
  int wv = t >> 6, lane = t & 63;
  int l15 = lane & 15, l4 = lane >> 4;
  float vbp[8], vbn[8];
#pragma unroll
  for (int nt = 0; nt < 8; ++nt) {
    vbp[nt] = bp[nt * 16 + l15];
    vbn[nt] = bn[nt * 16 + l15];
  }
  for (int c = blockIdx.x; c < nchunks; c += gridDim.x) {
    int rowbase = c * 128 + wv * 32;
    int r0 = rowbase + l15;      if (r0 >= nrows) r0 = nrows - 1;
    int r1 = rowbase + 16 + l15; if (r1 >= nrows) r1 = nrows - 1;
    f32x4 accP[2][8], accN[2][8];
#pragma unroll
    for (int rt = 0; rt < 2; ++rt)
#pragma unroll
      for (int nt = 0; nt < 8; ++nt) { accP[rt][nt] = (f32x4)(0.f); accN[rt][nt] = (f32x4)(0.f); }
#pragma unroll
    for (int kc = 0; kc < 4; ++kc) {
      int koff = kc * 32 + l4 * 8;
      bfrag aP0 = *(const bfrag*)(up + (size_t)r0 * 128 + koff);
      bfrag aP1 = *(const bfrag*)(up + (size_t)r1 * 128 + koff);
      bfrag aN0 = *(const bfrag*)(un + (size_t)r0 * 128 + koff);
      bfrag aN1 = *(const bfrag*)(un + (size_t)r1 * 128 + koff);
#pragma unroll
      for (int nt = 0; nt < 8; ++nt) {
        int col = nt * 16 + l15;
        int bb = (col * 256 + kc * 64 + l4 * 16) ^ ((col & 7) << 4);
        bfrag bP = *(const bfrag*)((const char*)wl + bb);
        bfrag bN = *(const bfrag*)((const char*)wl + 32768 + bb);
        accP[0][nt] = __builtin_amdgcn_mfma_f32_16x16x32_bf16(aP0, bP, accP[0][nt], 0, 0, 0);
        accP[1][nt] = __builtin_amdgcn_mfma_f32_16x16x32_bf16(aP1, bP, accP[1][nt], 0, 0, 0);
        accN[0][nt] = __builtin_amdgcn_mfma_f32_16x16x32_bf16(aN0, bN, accN[0][nt], 0, 0, 0);
        accN[1][nt] = __builtin_amdgcn_mfma_f32_16x16x32_bf16(aN1, bN, accN[1][nt], 0, 0, 0);
      }
    }
    if (do_pool) {
      // ---- fused mean-pool partial sums (last layer): no global h writes ----
      int crow0 = c * 128;
      int crow1 = crow0 + 127; if (crow1 >= nrows) crow1 = nrows - 1;
      int g0 = batch[crow0], g1 = batch[crow1];
      if (t < 128) pacc[t] = 0.f;
      __syncthreads();
      if (g0 == g1) {
#pragma unroll
        for (int nt = 0; nt < 8; ++nt) {
          float s = 0.f;
#pragma unroll
          for (int rt = 0; rt < 2; ++rt) {
#pragma unroll
            for (int r = 0; r < 4; ++r) {
              int row = rowbase + rt * 16 + l4 * 4 + r;
              float vp = accP[rt][nt][r] + vbp[nt]; vp = vp > 0.f ? vp : 0.f;
              float vn = accN[rt][nt][r] + vbn[nt]; vn = vn > 0.f ? vn : 0.f;
              s += (row < nrows) ? (vp - vn) : 0.f;
            }
          }
          s += __shfl_xor(s, 16, 64);
          s += __shfl_xor(s, 32, 64);
          if (l4 == 0) atomicAdd(&pacc[nt * 16 + l15], s);
        }
        __syncthreads();
        if (t < 128) atomicAdd(&pooled[g0 * 128 + t], pacc[t]);
      } else {
        for (int g = g0; g <= g1; ++g) {
#pragma unroll
          for (int nt = 0; nt < 8; ++nt) {
            float s = 0.f;
#pragma unroll
            for (int rt = 0; rt < 2; ++rt) {
#pragma unroll
              for (int r = 0; r < 4; ++r) {
                int row = rowbase + rt * 16 + l4 * 4 + r;
                bool in = (row < nrows) && (batch[row] == g);
                float vp = accP[rt][nt][r] + vbp[nt]; vp = vp > 0.f ? vp : 0.f;
                float vn = accN[rt][nt][r] + vbn[nt]; vn = vn > 0.f ? vn : 0.f;
                s += in ? (vp - vn) : 0.f;
              }
            }
            s += __shfl_xor(s, 16, 64);
            s += __shfl_xor(s, 32, 64);
            if (l4 == 0) atomicAdd(&pooled[g * 128 + nt * 16 + l15], s);
          }
        }
        __syncthreads();   // keep barrier count uniform with fast path
      }
      __syncthreads();     // pacc reuse guard for next chunk
      continue;
    }
    // epilogue: fp8 shadows only (two phases through the same ct8 buffer)
#pragma unroll
    for (int rt = 0; rt < 2; ++rt) {
#pragma unroll
      for (int h = 0; h < 2; ++h) {
        if ((l4 >> 1) == h) {
          int lr = (l4 & 1) * 4;
#pragma unroll
          for (int r = 0; r < 4; ++r) {
            int rw = rowbase + rt * 16 + h * 8 + lr + r;
            if (rw >= nrows) rw = nrows - 1;
            float dpr = dpn[2 * rw];
#pragma unroll
            for (int nt = 0; nt < 8; ++nt) {
              int col = nt * 16 + l15;
              float vp = accP[rt][nt][r] + vbp[nt]; vp = vp > 0.f ? vp : 0.f;
              float vn = accN[rt][nt][r] + vbn[nt]; vn = vn > 0.f ? vn : 0.f;
              float hv = vp - vn;
              ct8[wv][lr + r][col] =
                  (uint8_t)(__builtin_amdgcn_cvt_pk_fp8_f32(dpr * hv, dpr * hv, 0u, false) & 0xffu);
            }
          }
        }
        {
          int lrow = lane >> 3, lch = lane & 7;
          int grow = rowbase + rt * 16 + h * 8 + lrow;
          uint4 b16 = *(const uint4*)&ct8[wv][lrow][lch * 16];
          if (grow < nrows)
            *(uint4*)(x8p + (size_t)grow * 128 + lch * 16) = b16;
        }
        // phase 2: n-shadow
        if ((l4 >> 1) == h) {
          int lr = (l4 & 1) * 4;
#pragma unroll
          for (int r = 0; r < 4; ++r) {
            int rw = rowbase + rt * 16 + h * 8 + lr + r;
            if (rw >= nrows) rw = nrows - 1;
            float dnr = dpn[2 * rw + 1];
#pragma unroll
            for (int nt = 0; nt < 8; ++nt) {
              int col = nt * 16 + l15;
              float vp = accP[rt][nt][r] + vbp[nt]; vp = vp > 0.f ? vp : 0.f;
              float vn = accN[rt][nt][r] + vbn[nt]; vn = vn > 0.f ? vn : 0.f;
              float hv = vp - vn;
              ct8[wv][lr + r][col] =
                  (uint8_t)(__builtin_amdgcn_cvt_pk_fp8_f32(dnr * hv, dnr * hv, 0u, false) & 0xffu);
            }
          }
        }
        {
          int lrow = lane >> 3, lch = lane & 7;
          int grow = rowbase + rt * 16 + h * 8 + lrow;
          uint4 b16 = *(const uint4*)&ct8[wv][lrow][lch * 16];
          if (grow < nrows)
            *(uint4*)(x8n + (size_t)grow * 128 + lch * 16) = b16;
        }
      }
    }
  }
}

// ---- LayerNorm over D=128, one wave per graph; count via binary search ----
__global__ void k_ln(const float* __restrict__ pooled, const int* __restrict__ batch,
                     const float* __restrict__ gamma, const float* __restrict__ beta,
                     float* __restrict__ out, int G, int n) {
  int gid = blockIdx.x * blockDim.x + threadIdx.x;
  int g = gid >> 6, lane = gid & 63;
  if (g >= G) return;
  int lo = 0, hi = n;
  while (lo < hi) { int m = (lo + hi) >> 1; if (batch[m] < g) lo = m + 1; else hi = m; }
  int s0 = lo;
  lo = s0; hi = n;
  while (lo < hi) { int m = (lo + hi) >> 1; if (batch[m] < g + 1) lo = m + 1; else hi = m; }
  int e0 = lo;
  float2 s = ((const float2*)pooled)[g * 64 + lane];
  float cm = fmaxf((float)(e0 - s0), 1.f);
  float v0 = s.x / cm, v1 = s.y / cm;
  float tsum = v0 + v1;
#pragma unroll
  for (int m = 1; m < 64; m <<= 1) tsum += __shfl_xor(tsum, m, 64);
  float mu = tsum * (1.f / 128.f);
  float d0 = v0 - mu, d1 = v1 - mu;
  float q = d0 * d0 + d1 * d1;
#pragma unroll
  for (int m = 1; m < 64; m <<= 1) q += __shfl_xor(q, m, 64);
  float inv = rsqrtf(q * (1.f / 128.f) + 1e-5f);
  int f = 2 * lane;
  out[g * 128 + f]     = d0 * inv * gamma[f]     + beta[f];
  out[g * 128 + f + 1] = d1 * inv * gamma[f + 1] + beta[f + 1];
}

extern "C" void kernel_launch(void* const* d_in, const int* in_sizes, int n_in,
                              void* d_out, int out_size, void* d_ws, size_t ws_size,
                              hipStream_t stream) {
  const float* x     = (const float*)d_in[0];
  const int* ei      = (const int*)d_in[1];   // harness converts int64 -> int32
  const float* ew    = (const float*)d_in[2];
  const int* bt      = (const int*)d_in[3];   // int32
  const float* Wp    = (const float*)d_in[4];
  const float* bp    = (const float*)d_in[5];
  const float* Wn    = (const float*)d_in[6];
  const float* bn    = (const float*)d_in[7];
  const float* gamma = (const float*)d_in[8];
  const float* beta  = (const float*)d_in[9];
  int N = in_sizes[0] / 128;
  int E = in_sizes[1] / 2;
  int L = in_sizes[4] / (128 * 128);
  int G = out_size / 128;
  int nbk = (N + 63) / 64;          // coarse buckets (64 nodes)
  int nba = (E + 8191) / 8192;      // hist/part blocks (8k edges each)
  int SM = nbk * nba;               // scan size

  char* w = (char*)d_ws;
  auto alloc = [&](size_t bytes) {
    char* p = w;
    w += (bytes + 255) & ~(size_t)255;
    return p;
  };
  uint8_t* X8p   = (uint8_t*)alloc((size_t)N * 128 + 256); // dp[s]*h (fp8)
  uint8_t* X8n   = (uint8_t*)alloc((size_t)N * 128 + 256); // dn[s]*h (fp8)
  uint32_t* U    = (uint32_t*)alloc((size_t)N * 128 * 2);  // pos-branch agg (bf16)
  uint32_t* V    = (uint32_t*)alloc((size_t)N * 128 * 2);  // neg-branch agg (bf16)
  u16* wt        = (u16*)alloc((size_t)L * 2 * 128 * 128 * 2);
  uint32_t* rec4 = (uint32_t*)alloc(((size_t)E + 32) * 4); // bucket-major packed
  uint32_t* recF = (uint32_t*)alloc(((size_t)E + 32) * 4); // dst+sign-grouped final
  int* histA     = (int*)alloc((size_t)SM * 4);
  int* offsA     = (int*)alloc((size_t)(SM + 1) * 4);
  int* partA     = (int*)alloc(1024 * 4);
  int* bnd2      = (int*)alloc((size_t)(2 * N + 1) * 4);
  float* dpn     = (float*)alloc((size_t)N * 8);
  float* pooled  = (float*)alloc((size_t)G * 128 * 4);

  hipMemsetAsync(pooled, 0, (size_t)G * 128 * 4, stream);

  int wtot = L * 2 * 128 * 128;
  k_cvt_w<<<(wtot + 255) / 256, 256, 0, stream>>>(Wp, Wn, wt, wtot);
  k_histA<<<nba, 256, 0, stream>>>(ei, ew, histA, E, nbk, nba);
  int NB1 = (SM + 1023) / 1024;
  k_scan1<<<NB1, 1024, 0, stream>>>(histA, offsA, partA, SM);
  k_scan2<<<1, 1024, 0, stream>>>(partA, offsA, recF, NB1, SM);
  k_partB<<<nba, 256, 0, stream>>>(ei, ew, offsA, partA, rec4, E, nbk, nba);
  k_sortC<<<nbk, 256, 0, stream>>>(rec4, offsA, partA, recF, bnd2, dpn, N, nbk, nba, SM);
  k_shadow<<<((size_t)N * 64 + 255) / 256, 256, 0, stream>>>(x, dpn, X8p, X8n, N);

  int nchunks = (N + 127) / 128;
  for (int l = 0; l < L; ++l) {
    k_agg<<<((size_t)N * 64 + 255) / 256, 256, 0, stream>>>(X8p, X8n, bnd2, recF, dpn, U, V, N);
    k_gemm<<<512, 256, 0, stream>>>((const short*)U, (const short*)V,
                                    wt + (size_t)l * 32768, bp + (size_t)l * 128,
                                    bn + (size_t)l * 128, dpn, bt,
                                    X8p, X8n, pooled, (l == L - 1) ? 1 : 0,
                                    N, nchunks);
  }
  k_ln<<<(G * 64 + 255) / 256, 256, 0, stream>>>(pooled, bt, gamma, beta, (float*)d_out, G, N);
}